// Round 4
// baseline (1010.524 us; speedup 1.0000x reference)
//
#include <hip/hip_runtime.h>
#include <stdint.h>

// ---------------------------------------------------------------------------
// Attention_global: B=8,C=48,H=W=256,HEADS=8,FCT=16 -> per (b,head): N=256
// tokens (n=fx*16+fy), d=1536 (d=c*256+h*16+w), c=6.
// Pipeline (per split s in {q,k,v}: k_qkv1 -> k_dw) -> k_sgemm -> k_norms ->
// k_softmax -> k_ogemm -> k_proj.  Peak ws usage = 201,326,592 bytes.
// ---------------------------------------------------------------------------

#define DI __device__ __forceinline__
typedef __attribute__((ext_vector_type(8))) short short8;
typedef __attribute__((ext_vector_type(4))) float f32x4;

DI unsigned short f2bf(float f){
  unsigned u = __float_as_uint(f);
  unsigned r = (u + 0x7FFFu + ((u >> 16) & 1u)) >> 16;
  return (unsigned short)r;
}
DI float bf2f(unsigned short h){ return __uint_as_float(((unsigned)h) << 16); }

// ---------------------------------------------------------------------------
// K1a: qs[b][o][p] = sum_c wqs[o][c] * x[b][c][p]; one 48-ch split.
// MFMA M=48,K=48(pad 64),N=128 px/block. grid 4096. qs bf16 (b,48,65536).
// ---------------------------------------------------------------------------
__global__ __launch_bounds__(256) void k_qkv1(const float* __restrict__ x,
                                              const float* __restrict__ wqs,
                                              unsigned short* __restrict__ qs)
{
  __shared__ unsigned short sm[12672]; // A[48][72]@0 + B[128][72]@3456; reuse D[48][136]
  unsigned short* const lA = sm;
  unsigned short* const lB = sm + 3456;
  const int t = threadIdx.x;
  const int g0 = blockIdx.x << 7;
  const int b  = g0 >> 16;
  const int p0 = g0 & 65535;

  for (int i = t; i < 6336; i += 256) ((unsigned*)sm)[i] = 0u; // k-pad must be 0
  __syncthreads();
  for (int j = t; j < 2304; j += 256){
    int m = j / 48, k = j - m * 48;
    lA[m * 72 + k] = f2bf(wqs[j]);
  }
  // B = x^T tile [pixel][k=c]: bf16-pair pack + XOR block swizzle
  for (int j = t; j < 384; j += 256){
    int cp = j >> 4, nc = j & 15;
    const float* xr = x + ((size_t)(b * 48 + 2 * cp)) * 65536 + p0 + nc * 8;
    float4 a0 = *(const float4*)xr;
    float4 a1 = *(const float4*)(xr + 4);
    float4 b0 = *(const float4*)(xr + 65536);
    float4 b1 = *(const float4*)(xr + 65536 + 4);
    float r0[8] = {a0.x,a0.y,a0.z,a0.w,a1.x,a1.y,a1.z,a1.w};
    float r1[8] = {b0.x,b0.y,b0.z,b0.w,b1.x,b1.y,b1.z,b1.w};
    unsigned* dst = (unsigned*)lB;
    int cx = (nc & 7) << 2;
    #pragma unroll
    for (int i = 0; i < 8; i++)
      dst[(nc * 8 + i) * 36 + (cp ^ cx)] =
        (unsigned)f2bf(r0[i]) | ((unsigned)f2bf(r1[i]) << 16);
  }
  __syncthreads();

  const int lane = t & 63, wv = t >> 6;
  const int m15 = lane & 15, quad = lane >> 4;
  const int nw = wv << 5;
  f32x4 acc[3][2];
  f32x4 z = {0.f,0.f,0.f,0.f};
  #pragma unroll
  for (int i = 0; i < 3; i++){ acc[i][0] = z; acc[i][1] = z; }

  #pragma unroll
  for (int ks = 0; ks < 2; ks++){
    short8 bfr[2];
    #pragma unroll
    for (int nt = 0; nt < 2; nt++){
      int row = nw + nt * 16 + m15;
      bfr[nt] = *(const short8*)(lB + row * 72 + (((4 * ks + quad) ^ ((row >> 3) & 7)) << 3));
    }
    #pragma unroll
    for (int mt = 0; mt < 3; mt++){
      short8 afr = *(const short8*)(lA + (mt * 16 + m15) * 72 + ks * 32 + quad * 8);
      acc[mt][0] = __builtin_amdgcn_mfma_f32_16x16x32_bf16(afr, bfr[0], acc[mt][0], 0, 0, 0);
      acc[mt][1] = __builtin_amdgcn_mfma_f32_16x16x32_bf16(afr, bfr[1], acc[mt][1], 0, 0, 0);
    }
  }
  __syncthreads();
  #pragma unroll
  for (int mt = 0; mt < 3; mt++)
    #pragma unroll
    for (int nt = 0; nt < 2; nt++)
      #pragma unroll
      for (int r = 0; r < 4; r++)
        sm[(mt * 16 + quad * 4 + r) * 136 + nw + nt * 16 + m15] = f2bf(acc[mt][nt][r]);
  __syncthreads();
  for (int j = t; j < 768; j += 256){
    int o = j >> 4, oc = j & 15;
    *(uint4*)(qs + ((size_t)(b * 48 + o)) * 65536 + p0 + oc * 8) =
      *(const uint4*)(sm + o * 136 + oc * 8);
  }
}

// ---------------------------------------------------------------------------
// K1b: depthwise 3x3 (SAME) over qs (48 ch); writes tok bf16 (b,head,d,n)
// via swizzled LDS transpose. grid (2, 16, 8), block 256.
// ---------------------------------------------------------------------------
__global__ __launch_bounds__(256) void k_dw(const unsigned short* __restrict__ qs,
                                            const float* __restrict__ wds,
                                            unsigned short* __restrict__ tok)
{
  __shared__ float tile[9504];            // 4ch x 18 x 132
  __shared__ float wsh[432];              // 48ch x 9
  __shared__ unsigned short lout[8448];   // 4ch x 8wt x 264 (swizzled tokens)
  const int t = threadIdx.x;
  const int wg = blockIdx.x, h = blockIdx.y, b = blockIdx.z;
  const int y0 = h << 4, xg = wg << 7;
  const int x2 = t & 63, ys = t >> 6;

  for (int j = t; j < 432; j += 256) wsh[j] = wds[j];

  for (int cg = 0; cg < 12; cg++){
    __syncthreads();
    for (int j = t; j < 9360; j += 256){
      int cl = j / 2340; int r2 = j - cl * 2340;
      int row = r2 / 130; int col = r2 - row * 130;
      int y = y0 - 1 + row, xx = xg - 1 + col;
      float v = 0.f;
      if ((unsigned)y < 256u && (unsigned)xx < 256u)
        v = bf2f(qs[((size_t)(b * 48 + cg * 4 + cl)) * 65536 + y * 256 + xx]);
      tile[cl * 2376 + row * 132 + col] = v;
    }
    __syncthreads();
    #pragma unroll
    for (int cl = 0; cl < 4; cl++){
      int ch1 = cg * 4 + cl;
      float w9[9];
      #pragma unroll
      for (int i = 0; i < 9; i++) w9[i] = wsh[ch1 * 9 + i];
      float vreg[6][4];
      const float* tb = tile + cl * 2376;
      #pragma unroll
      for (int rr = 0; rr < 6; rr++)
        #pragma unroll
        for (int c4 = 0; c4 < 4; c4++)
          vreg[rr][c4] = tb[(ys * 4 + rr) * 132 + 2 * x2 + c4];
      #pragma unroll
      for (int r = 0; r < 4; r++)
        #pragma unroll
        for (int xx2 = 0; xx2 < 2; xx2++){
          float s = 0.f;
          #pragma unroll
          for (int dy = 0; dy < 3; dy++)
            #pragma unroll
            for (int dx = 0; dx < 3; dx++)
              s = fmaf(vreg[r + dy][xx2 + dx], w9[dy * 3 + dx], s);
          int xl = 2 * x2 + xx2;
          int n = ((xl & 15) << 4) + ys * 4 + r;
          lout[cl * 2112 + (xl >> 4) * 264 + ((n & 0xF0) | ((n & 15) ^ (n >> 4)))] = f2bf(s);
        }
    }
    __syncthreads();
    for (int j = t; j < 1024; j += 256){
      int cl = j >> 8, wt = (j >> 5) & 7, oc = j & 31;
      int ch1 = cg * 4 + cl;
      int head = ch1 / 6, cc = ch1 - head * 6;
      int d = cc * 256 + h * 16 + wg * 8 + wt;
      const unsigned short* lp = lout + cl * 2112 + wt * 264;
      unsigned short v8[8];
      #pragma unroll
      for (int i = 0; i < 8; i++){
        int n = oc * 8 + i;
        v8[i] = lp[(n & 0xF0) | ((n & 15) ^ (n >> 4))];
      }
      uint4 pk;
      pk.x = (unsigned)v8[0] | ((unsigned)v8[1] << 16);
      pk.y = (unsigned)v8[2] | ((unsigned)v8[3] << 16);
      pk.z = (unsigned)v8[4] | ((unsigned)v8[5] << 16);
      pk.w = (unsigned)v8[6] | ((unsigned)v8[7] << 16);
      *(uint4*)(tok + (((size_t)(b * 8 + head)) * 1536 + d) * 256 + oc * 8) = pk;
    }
  }
}

// ---------------------------------------------------------------------------
// K2: nq[bh][n] = sum_d Qd[bh][d][n]^2 (same for nk/Kd). grid 128, blk 256.
// ---------------------------------------------------------------------------
__global__ __launch_bounds__(256) void k_norms(const unsigned short* __restrict__ Qd,
                                               const unsigned short* __restrict__ Kd,
                                               float* __restrict__ nq,
                                               float* __restrict__ nk)
{
  const int bh = blockIdx.x >> 1;
  const unsigned short* T = (blockIdx.x & 1) ? Kd : Qd;
  float* N = (blockIdx.x & 1) ? nk : nq;
  const int n = threadIdx.x;
  const unsigned short* p = T + (size_t)bh * 393216 + n;
  float s = 0.f;
  #pragma unroll 8
  for (int d = 0; d < 1536; d++){ float v = bf2f(p[(size_t)d * 256]); s = fmaf(v, v, s); }
  N[bh * 256 + n] = s;
}

// ---------------------------------------------------------------------------
// K3: S[bh][n][m] = sum_d Q[bh][d][n]*K[bh][d][m]. 128x128/block, grid (4,64).
// ---------------------------------------------------------------------------
__global__ __launch_bounds__(256) void k_sgemm(const unsigned short* __restrict__ Qd,
                                               const unsigned short* __restrict__ Kd,
                                               float* __restrict__ S)
{
  __shared__ unsigned short sm[18432];
  unsigned short* const sa = sm;
  unsigned short* const sb = sm + 9216;
  const int t = threadIdx.x;
  const int bh = blockIdx.y;
  const int n0 = (blockIdx.x >> 1) << 7;
  const int m0 = (blockIdx.x & 1) << 7;
  const int lane = t & 63, wv = t >> 6;
  const int m15 = lane & 15, quad = lane >> 4;
  const int wm = (wv & 1) << 6, wn = (wv >> 1) << 6;
  const size_t base = (size_t)bh * 393216;
  f32x4 acc[4][4];
  f32x4 z = {0.f,0.f,0.f,0.f};
  #pragma unroll
  for (int i = 0; i < 4; i++)
    #pragma unroll
    for (int j = 0; j < 4; j++) acc[i][j] = z;

  for (int s = 0; s < 24; s++){
    __syncthreads();
    for (int j = t; j < 1024; j += 256){
      int hf = j >> 9, jj = j & 511;
      int kp = jj >> 4, nc = jj & 15;
      const unsigned short* src = (hf ? Kd : Qd) + base
        + (size_t)(s * 64 + 2 * kp) * 256 + (hf ? m0 : n0) + nc * 8;
      uint4 q0 = *(const uint4*)src;
      uint4 q1 = *(const uint4*)(src + 256);
      const unsigned short* u0 = (const unsigned short*)&q0;
      const unsigned short* u1 = (const unsigned short*)&q1;
      unsigned* dst = (unsigned*)(hf ? sb : sa);
      int cx = (nc & 7) << 2;
      #pragma unroll
      for (int i = 0; i < 8; i++)
        dst[(nc * 8 + i) * 36 + (kp ^ cx)] = (unsigned)u0[i] | ((unsigned)u1[i] << 16);
    }
    __syncthreads();
    #pragma unroll
    for (int ks = 0; ks < 2; ks++){
      short8 afr[4], bfr[4];
      #pragma unroll
      for (int i = 0; i < 4; i++){
        int ra = wm + i * 16 + m15;
        int rb = wn + i * 16 + m15;
        afr[i] = *(const short8*)(sa + ra * 72 + (((4 * ks + quad) ^ ((ra >> 3) & 7)) << 3));
        bfr[i] = *(const short8*)(sb + rb * 72 + (((4 * ks + quad) ^ ((rb >> 3) & 7)) << 3));
      }
      #pragma unroll
      for (int mi = 0; mi < 4; mi++)
        #pragma unroll
        for (int ni = 0; ni < 4; ni++)
          acc[mi][ni] = __builtin_amdgcn_mfma_f32_16x16x32_bf16(afr[mi], bfr[ni], acc[mi][ni], 0, 0, 0);
    }
  }
  #pragma unroll
  for (int mi = 0; mi < 4; mi++)
    #pragma unroll
    for (int ni = 0; ni < 4; ni++)
      #pragma unroll
      for (int r = 0; r < 4; r++){
        int nr = n0 + wm + mi * 16 + quad * 4 + r;
        int mc = m0 + wn + ni * 16 + m15;
        S[(size_t)bh * 65536 + (size_t)nr * 256 + mc] = acc[mi][ni][r];
      }
}

// ---------------------------------------------------------------------------
// K4: softmax_1 with l2-norm scaling + temperature (NaN-proofed clamps).
// ---------------------------------------------------------------------------
__global__ __launch_bounds__(256) void k_softmax(const float* __restrict__ S,
                                                 const float* __restrict__ nq,
                                                 const float* __restrict__ nk,
                                                 const float* __restrict__ temp,
                                                 unsigned short* __restrict__ P)
{
  const int t = threadIdx.x, lane = t & 63, wv = t >> 6;
  const int bh = blockIdx.y;
  const int n = blockIdx.x * 4 + wv;
  const float tp = temp[bh & 7];
  const size_t ro = (size_t)bh * 65536 + (size_t)n * 256;
  float4 sv = *(const float4*)(S + ro + lane * 4);
  float4 k4 = *(const float4*)(nk + (size_t)bh * 256 + lane * 4);
  float qi = tp / fmaxf(sqrtf(fmaxf(nq[(size_t)bh * 256 + n], 0.f)), 1e-12f);
  float i0 = 1.f / fmaxf(sqrtf(fmaxf(k4.x, 0.f)), 1e-12f);
  float i1 = 1.f / fmaxf(sqrtf(fmaxf(k4.y, 0.f)), 1e-12f);
  float i2 = 1.f / fmaxf(sqrtf(fmaxf(k4.z, 0.f)), 1e-12f);
  float i3 = 1.f / fmaxf(sqrtf(fmaxf(k4.w, 0.f)), 1e-12f);
  float e0 = __expf(fminf(sv.x * qi * i0, 60.f));
  float e1 = __expf(fminf(sv.y * qi * i1, 60.f));
  float e2 = __expf(fminf(sv.z * qi * i2, 60.f));
  float e3 = __expf(fminf(sv.w * qi * i3, 60.f));
  float ss = e0 + e1 + e2 + e3;
  #pragma unroll
  for (int o = 32; o > 0; o >>= 1) ss += __shfl_xor(ss, o);
  float inv = 1.f / (ss + 1.f);
  uint2 pv;
  pv.x = (unsigned)f2bf(e0 * inv) | ((unsigned)f2bf(e1 * inv) << 16);
  pv.y = (unsigned)f2bf(e2 * inv) | ((unsigned)f2bf(e3 * inv) << 16);
  *(uint2*)(P + ro + lane * 4) = pv;
}

// ---------------------------------------------------------------------------
// K5: O[bh][d][n] = sum_m V[bh][d][m] * P[bh][n][m]. 128x128/block, grid(24,64).
// ---------------------------------------------------------------------------
__global__ __launch_bounds__(256) void k_ogemm(const unsigned short* __restrict__ Vd,
                                               const unsigned short* __restrict__ P,
                                               unsigned short* __restrict__ Od)
{
  __shared__ unsigned short sm[18432];
  unsigned short* const sa = sm;
  unsigned short* const sb = sm + 9216;
  const int t = threadIdx.x;
  const int bh = blockIdx.y;
  const int d0 = (blockIdx.x >> 1) << 7;
  const int n0 = (blockIdx.x & 1) << 7;
  const int lane = t & 63, wv = t >> 6;
  const int m15 = lane & 15, quad = lane >> 4;
  const int wm = (wv & 1) << 6, wn = (wv >> 1) << 6;
  f32x4 acc[4][4];
  f32x4 z = {0.f,0.f,0.f,0.f};
  #pragma unroll
  for (int i = 0; i < 4; i++)
    #pragma unroll
    for (int j = 0; j < 4; j++) acc[i][j] = z;

  for (int s = 0; s < 4; s++){
    __syncthreads();
    for (int j = t; j < 512; j += 256){
      int hf = j >> 8, jj = j & 255;
      int row = jj >> 1, hh = jj & 1;
      const unsigned short* src = hf
        ? (P  + (size_t)bh * 65536  + (size_t)(n0 + row) * 256 + s * 64 + hh * 32)
        : (Vd + (size_t)bh * 393216 + (size_t)(d0 + row) * 256 + s * 64 + hh * 32);
      uint4 v0 = *(const uint4*)src;
      uint4 v1 = *(const uint4*)(src + 8);
      uint4 v2 = *(const uint4*)(src + 16);
      uint4 v3 = *(const uint4*)(src + 24);
      unsigned* dst = (unsigned*)(hf ? sb : sa) + row * 36 + hh * 16;
      *(uint4*)dst        = v0;
      *(uint4*)(dst + 4)  = v1;
      *(uint4*)(dst + 8)  = v2;
      *(uint4*)(dst + 12) = v3;
    }
    __syncthreads();
    #pragma unroll
    for (int ks = 0; ks < 2; ks++){
      short8 afr[4], bfr[4];
      #pragma unroll
      for (int i = 0; i < 4; i++){
        afr[i] = *(const short8*)(sa + (wm + i * 16 + m15) * 72 + ks * 32 + quad * 8);
        bfr[i] = *(const short8*)(sb + (wn + i * 16 + m15) * 72 + ks * 32 + quad * 8);
      }
      #pragma unroll
      for (int mi = 0; mi < 4; mi++)
        #pragma unroll
        for (int ni = 0; ni < 4; ni++)
          acc[mi][ni] = __builtin_amdgcn_mfma_f32_16x16x32_bf16(afr[mi], bfr[ni], acc[mi][ni], 0, 0, 0);
    }
  }
  __syncthreads();
  #pragma unroll
  for (int mi = 0; mi < 4; mi++)
    #pragma unroll
    for (int ni = 0; ni < 4; ni++)
      #pragma unroll
      for (int r = 0; r < 4; r++)
        sm[(wm + mi * 16 + quad * 4 + r) * 136 + wn + ni * 16 + m15] = f2bf(acc[mi][ni][r]);
  __syncthreads();
  {
    int row = t >> 1, hh = t & 1;
    const unsigned short* lp = sm + row * 136 + hh * 64;
    unsigned short* gp = Od + (size_t)bh * 393216 + (size_t)(d0 + row) * 256 + n0 + hh * 64;
    #pragma unroll
    for (int u = 0; u < 8; u++)
      *(uint4*)(gp + u * 8) = *(const uint4*)(lp + u * 8);
  }
}

// ---------------------------------------------------------------------------
// K6: out[b][o][y][x] = sum_c48 wp[o][c] * Osp[b][c][y][x]. grid (16,16,8).
// ---------------------------------------------------------------------------
__global__ __launch_bounds__(256) void k_proj(const unsigned short* __restrict__ Od,
                                              const float* __restrict__ wp,
                                              float* __restrict__ out)
{
  __shared__ unsigned short sm6[21888];   // B[256][72]@0 + A[48][72]@18432; reuse lo fp32[16][264]
  unsigned short* const lb = sm6;
  unsigned short* const la = sm6 + 18432;
  float* const lo = (float*)sm6;
  const int t = threadIdx.x;
  const int w = blockIdx.x, h = blockIdx.y, b = blockIdx.z;
  for (int j = t; j < 10944; j += 256) ((unsigned*)sm6)[j] = 0u;
  __syncthreads();
  for (int j = t; j < 2304; j += 256){
    int m = j / 48, k = j - m * 48;
    la[m * 72 + k] = f2bf(wp[j]);
  }
  for (int j = t; j < 768; j += 256){
    int cp = j >> 5, nc = j & 31;
    int ch0 = 2 * cp;
    int head = ch0 / 6, cc = ch0 - head * 6;
    const unsigned short* r0 = Od + (((size_t)(b * 8 + head)) * 1536 + cc * 256 + h * 16 + w) * 256 + nc * 8;
    uint4 q0 = *(const uint4*)r0;
    uint4 q1 = *(const uint4*)(r0 + 65536);  // FIXED: channel+1 is d+256 -> +65536 shorts (was +256 = w+1!)
    const unsigned short* u0 = (const unsigned short*)&q0;
    const unsigned short* u1 = (const unsigned short*)&q1;
    unsigned* dst = (unsigned*)lb;
    int cx = (nc & 7) << 2;
    #pragma unroll
    for (int i = 0; i < 8; i++)
      dst[(nc * 8 + i) * 36 + (cp ^ cx)] = (unsigned)u0[i] | ((unsigned)u1[i] << 16);
  }
  __syncthreads();

  const int lane = t & 63, wv = t >> 6;
  const int m15 = lane & 15, quad = lane >> 4;
  const int n0w = wv << 6;
  f32x4 acc[3][4];
  f32x4 z = {0.f,0.f,0.f,0.f};
  #pragma unroll
  for (int i = 0; i < 3; i++)
    #pragma unroll
    for (int j = 0; j < 4; j++) acc[i][j] = z;
  #pragma unroll
  for (int ks = 0; ks < 2; ks++){
    short8 bfr[4];
    #pragma unroll
    for (int nt = 0; nt < 4; nt++){
      int rb = n0w + nt * 16 + m15;
      bfr[nt] = *(const short8*)(lb + rb * 72 + (((4 * ks + quad) ^ ((rb >> 3) & 7)) << 3));
    }
    #pragma unroll
    for (int mt = 0; mt < 3; mt++){
      short8 afr = *(const short8*)(la + (mt * 16 + m15) * 72 + ks * 32 + quad * 8);
      #pragma unroll
      for (int nt = 0; nt < 4; nt++)
        acc[mt][nt] = __builtin_amdgcn_mfma_f32_16x16x32_bf16(afr, bfr[nt], acc[mt][nt], 0, 0, 0);
    }
  }
  for (int mt = 0; mt < 3; mt++){
    __syncthreads();
    #pragma unroll
    for (int nt = 0; nt < 4; nt++)
      #pragma unroll
      for (int r = 0; r < 4; r++){
        int n = n0w + nt * 16 + m15;
        lo[(quad * 4 + r) * 264 + ((n & 0xF0) | ((n & 15) ^ (n >> 4)))] = acc[mt][nt][r];
      }
    __syncthreads();
    int fy = t >> 4, fx = t & 15;
    #pragma unroll
    for (int r = 0; r < 16; r++){
      float v = lo[r * 264 + fx * 16 + (fy ^ fx)];
      out[((size_t)(b * 48 + mt * 16 + r)) * 65536 + (h * 16 + fy) * 256 + w * 16 + fx] = v;
    }
  }
}

// ---------------------------------------------------------------------------
extern "C" void kernel_launch(void* const* d_in, const int* in_sizes, int n_in,
                              void* d_out, int out_size, void* d_ws, size_t ws_size,
                              hipStream_t stream)
{
  (void)in_sizes; (void)n_in; (void)out_size; (void)ws_size;
  const float* x  = (const float*)d_in[0];
  const float* wq = (const float*)d_in[1];
  const float* wd = (const float*)d_in[2];
  const float* wp = (const float*)d_in[3];
  const float* tp = (const float*)d_in[4];
  float* out = (float*)d_out;
  char* ws = (char*)d_ws;

  unsigned short* qs = (unsigned short*)ws;                  // [0, 50.33 MB) scratch per split
  unsigned short* Qd = (unsigned short*)(ws + 50331648);
  unsigned short* Kd = (unsigned short*)(ws + 100663296);
  unsigned short* Vd = (unsigned short*)(ws + 150994944);
  float*          S  = (float*)ws;                           // reuses qs region (dead)
  unsigned short* P  = (unsigned short*)(ws + 16777216);
  float*          nq = (float*)(ws + 25165824);
  float*          nk = (float*)(ws + 25231360);
  unsigned short* Od = Qd;                                   // reuses Qd (dead after sgemm/norms)
  unsigned short* toks[3] = {Qd, Kd, Vd};

  for (int split = 0; split < 3; split++){
    k_qkv1<<<4096,             256, 0, stream>>>(x, wq + split * 2304, qs);
    k_dw  <<<dim3(2, 16, 8),   256, 0, stream>>>(qs, wd + split * 432, toks[split]);
  }
  k_sgemm  <<<dim3(4, 64),     256, 0, stream>>>(Qd, Kd, S);
  k_norms  <<<128,             256, 0, stream>>>(Qd, Kd, nq, nk);
  k_softmax<<<dim3(64, 64),    256, 0, stream>>>(S, nq, nk, tp, P);
  k_ogemm  <<<dim3(24, 64),    256, 0, stream>>>(Vd, P, Od);
  k_proj   <<<dim3(16, 16, 8), 256, 0, stream>>>(Od, wp, out);
}

// Round 5
// 722.208 us; speedup vs baseline: 1.3992x; 1.3992x over previous
//
#include <hip/hip_runtime.h>
#include <stdint.h>

// ---------------------------------------------------------------------------
// Attention_global: B=8,C=48,H=W=256,HEADS=8,FCT=16 -> per (b,head): N=256
// tokens (n=fx*16+fy), d=1536 (d=c*256+h*16+w), c=6.
// Pipeline (per split s in {q,k,v}: k_qkv1 -> k_dw) -> k_sgemm -> k_norms ->
// k_softmax -> k_ogemm -> k_proj.  Peak ws usage = 201,326,592 bytes.
// R5: k_dw cg-loop -> grid (256->3072 blocks); k_norms vectorized+shfl-reduce.
// ---------------------------------------------------------------------------

#define DI __device__ __forceinline__
typedef __attribute__((ext_vector_type(8))) short short8;
typedef __attribute__((ext_vector_type(4))) float f32x4;

DI unsigned short f2bf(float f){
  unsigned u = __float_as_uint(f);
  unsigned r = (u + 0x7FFFu + ((u >> 16) & 1u)) >> 16;
  return (unsigned short)r;
}
DI float bf2f(unsigned short h){ return __uint_as_float(((unsigned)h) << 16); }

// ---------------------------------------------------------------------------
// K1a: qs[b][o][p] = sum_c wqs[o][c] * x[b][c][p]; one 48-ch split.
// MFMA M=48,K=48(pad 64),N=128 px/block. grid 4096. qs bf16 (b,48,65536).
// ---------------------------------------------------------------------------
__global__ __launch_bounds__(256) void k_qkv1(const float* __restrict__ x,
                                              const float* __restrict__ wqs,
                                              unsigned short* __restrict__ qs)
{
  __shared__ unsigned short sm[12672]; // A[48][72]@0 + B[128][72]@3456; reuse D[48][136]
  unsigned short* const lA = sm;
  unsigned short* const lB = sm + 3456;
  const int t = threadIdx.x;
  const int g0 = blockIdx.x << 7;
  const int b  = g0 >> 16;
  const int p0 = g0 & 65535;

  for (int i = t; i < 6336; i += 256) ((unsigned*)sm)[i] = 0u; // k-pad must be 0
  __syncthreads();
  for (int j = t; j < 2304; j += 256){
    int m = j / 48, k = j - m * 48;
    lA[m * 72 + k] = f2bf(wqs[j]);
  }
  // B = x^T tile [pixel][k=c]: bf16-pair pack + XOR block swizzle
  for (int j = t; j < 384; j += 256){
    int cp = j >> 4, nc = j & 15;
    const float* xr = x + ((size_t)(b * 48 + 2 * cp)) * 65536 + p0 + nc * 8;
    float4 a0 = *(const float4*)xr;
    float4 a1 = *(const float4*)(xr + 4);
    float4 b0 = *(const float4*)(xr + 65536);
    float4 b1 = *(const float4*)(xr + 65536 + 4);
    float r0[8] = {a0.x,a0.y,a0.z,a0.w,a1.x,a1.y,a1.z,a1.w};
    float r1[8] = {b0.x,b0.y,b0.z,b0.w,b1.x,b1.y,b1.z,b1.w};
    unsigned* dst = (unsigned*)lB;
    int cx = (nc & 7) << 2;
    #pragma unroll
    for (int i = 0; i < 8; i++)
      dst[(nc * 8 + i) * 36 + (cp ^ cx)] =
        (unsigned)f2bf(r0[i]) | ((unsigned)f2bf(r1[i]) << 16);
  }
  __syncthreads();

  const int lane = t & 63, wv = t >> 6;
  const int m15 = lane & 15, quad = lane >> 4;
  const int nw = wv << 5;
  f32x4 acc[3][2];
  f32x4 z = {0.f,0.f,0.f,0.f};
  #pragma unroll
  for (int i = 0; i < 3; i++){ acc[i][0] = z; acc[i][1] = z; }

  #pragma unroll
  for (int ks = 0; ks < 2; ks++){
    short8 bfr[2];
    #pragma unroll
    for (int nt = 0; nt < 2; nt++){
      int row = nw + nt * 16 + m15;
      bfr[nt] = *(const short8*)(lB + row * 72 + (((4 * ks + quad) ^ ((row >> 3) & 7)) << 3));
    }
    #pragma unroll
    for (int mt = 0; mt < 3; mt++){
      short8 afr = *(const short8*)(lA + (mt * 16 + m15) * 72 + ks * 32 + quad * 8);
      acc[mt][0] = __builtin_amdgcn_mfma_f32_16x16x32_bf16(afr, bfr[0], acc[mt][0], 0, 0, 0);
      acc[mt][1] = __builtin_amdgcn_mfma_f32_16x16x32_bf16(afr, bfr[1], acc[mt][1], 0, 0, 0);
    }
  }
  __syncthreads();
  #pragma unroll
  for (int mt = 0; mt < 3; mt++)
    #pragma unroll
    for (int nt = 0; nt < 2; nt++)
      #pragma unroll
      for (int r = 0; r < 4; r++)
        sm[(mt * 16 + quad * 4 + r) * 136 + nw + nt * 16 + m15] = f2bf(acc[mt][nt][r]);
  __syncthreads();
  for (int j = t; j < 768; j += 256){
    int o = j >> 4, oc = j & 15;
    *(uint4*)(qs + ((size_t)(b * 48 + o)) * 65536 + p0 + oc * 8) =
      *(const uint4*)(sm + o * 136 + oc * 8);
  }
}

// ---------------------------------------------------------------------------
// K1b: depthwise 3x3 (SAME) over qs (48 ch); writes tok bf16 (b,head,d,n)
// via swizzled LDS transpose. grid (2, 16, 8*12=96): z=b*12+cg. block 256.
// R5: cg moved from serial loop into grid (12x parallelism).
// ---------------------------------------------------------------------------
__global__ __launch_bounds__(256) void k_dw(const unsigned short* __restrict__ qs,
                                            const float* __restrict__ wds,
                                            unsigned short* __restrict__ tok)
{
  __shared__ float tile[9504];            // 4ch x 18 x 132
  __shared__ unsigned short lout[8448];   // 4ch x 8wt x 264 (swizzled tokens)
  const int t = threadIdx.x;
  const int wg = blockIdx.x, h = blockIdx.y;
  const int b = blockIdx.z / 12, cg = blockIdx.z % 12;
  const int y0 = h << 4, xg = wg << 7;
  const int x2 = t & 63, ys = t >> 6;

  // stage 4 channels x 18 rows x 130 cols (halo, zero OOB)
  for (int j = t; j < 9360; j += 256){
    int cl = j / 2340; int r2 = j - cl * 2340;
    int row = r2 / 130; int col = r2 - row * 130;
    int y = y0 - 1 + row, xx = xg - 1 + col;
    float v = 0.f;
    if ((unsigned)y < 256u && (unsigned)xx < 256u)
      v = bf2f(qs[((size_t)(b * 48 + cg * 4 + cl)) * 65536 + y * 256 + xx]);
    tile[cl * 2376 + row * 132 + col] = v;
  }
  __syncthreads();
  #pragma unroll
  for (int cl = 0; cl < 4; cl++){
    int ch1 = cg * 4 + cl;
    float w9[9];
    #pragma unroll
    for (int i = 0; i < 9; i++) w9[i] = wds[ch1 * 9 + i];   // wave-uniform s-loads
    float vreg[6][4];
    const float* tb = tile + cl * 2376;
    #pragma unroll
    for (int rr = 0; rr < 6; rr++)
      #pragma unroll
      for (int c4 = 0; c4 < 4; c4++)
        vreg[rr][c4] = tb[(ys * 4 + rr) * 132 + 2 * x2 + c4];
    #pragma unroll
    for (int r = 0; r < 4; r++)
      #pragma unroll
      for (int xx2 = 0; xx2 < 2; xx2++){
        float s = 0.f;
        #pragma unroll
        for (int dy = 0; dy < 3; dy++)
          #pragma unroll
          for (int dx = 0; dx < 3; dx++)
            s = fmaf(vreg[r + dy][xx2 + dx], w9[dy * 3 + dx], s);
        int xl = 2 * x2 + xx2;
        int n = ((xl & 15) << 4) + ys * 4 + r;
        lout[cl * 2112 + (xl >> 4) * 264 + ((n & 0xF0) | ((n & 15) ^ (n >> 4)))] = f2bf(s);
      }
  }
  __syncthreads();
  // coalesced token-layout writeback
  for (int j = t; j < 1024; j += 256){
    int cl = j >> 8, wt = (j >> 5) & 7, oc = j & 31;
    int ch1 = cg * 4 + cl;
    int head = ch1 / 6, cc = ch1 - head * 6;
    int d = cc * 256 + h * 16 + wg * 8 + wt;
    const unsigned short* lp = lout + cl * 2112 + wt * 264;
    unsigned short v8[8];
    #pragma unroll
    for (int i = 0; i < 8; i++){
      int n = oc * 8 + i;
      v8[i] = lp[(n & 0xF0) | ((n & 15) ^ (n >> 4))];
    }
    uint4 pk;
    pk.x = (unsigned)v8[0] | ((unsigned)v8[1] << 16);
    pk.y = (unsigned)v8[2] | ((unsigned)v8[3] << 16);
    pk.z = (unsigned)v8[4] | ((unsigned)v8[5] << 16);
    pk.w = (unsigned)v8[6] | ((unsigned)v8[7] << 16);
    *(uint4*)(tok + (((size_t)(b * 8 + head)) * 1536 + d) * 256 + oc * 8) = pk;
  }
}

// ---------------------------------------------------------------------------
// K2: norm partials. grid (64 bh, 2 tensor, 2 d-half), block 256 = 32 n-octets
// x 8 d-groups (g = t&7 -> in-wave shfl reduce). Writes [half][bh][256].
// ---------------------------------------------------------------------------
__global__ __launch_bounds__(256) void k_norms(const unsigned short* __restrict__ Qd,
                                               const unsigned short* __restrict__ Kd,
                                               float* __restrict__ nqp,
                                               float* __restrict__ nkp)
{
  const int bh = blockIdx.x, half = blockIdx.z;
  const unsigned short* T = blockIdx.y ? Kd : Qd;
  float* N = blockIdx.y ? nkp : nqp;
  const int t = threadIdx.x, g = t & 7, tl = t >> 3;
  const unsigned short* p = T + (size_t)bh * 393216 + (size_t)(half * 768 + g) * 256 + tl * 8;
  float a[8] = {0.f,0.f,0.f,0.f,0.f,0.f,0.f,0.f};
  #pragma unroll 4
  for (int dd = 0; dd < 96; dd++){
    uint4 v = *(const uint4*)(p + (size_t)dd * 2048);
    const unsigned short* u = (const unsigned short*)&v;
    #pragma unroll
    for (int i = 0; i < 8; i++){ float f = bf2f(u[i]); a[i] = fmaf(f, f, a[i]); }
  }
  #pragma unroll
  for (int off = 1; off < 8; off <<= 1)
    #pragma unroll
    for (int i = 0; i < 8; i++) a[i] += __shfl_xor(a[i], off);
  if (g == 0){
    float* o = N + half * 16384 + bh * 256 + tl * 8;
    #pragma unroll
    for (int i = 0; i < 8; i++) o[i] = a[i];
  }
}

// ---------------------------------------------------------------------------
// K3: S[bh][n][m] = sum_d Q[bh][d][n]*K[bh][d][m]. 128x128/block, grid (4,64).
// ---------------------------------------------------------------------------
__global__ __launch_bounds__(256) void k_sgemm(const unsigned short* __restrict__ Qd,
                                               const unsigned short* __restrict__ Kd,
                                               float* __restrict__ S)
{
  __shared__ unsigned short sm[18432];
  unsigned short* const sa = sm;
  unsigned short* const sb = sm + 9216;
  const int t = threadIdx.x;
  const int bh = blockIdx.y;
  const int n0 = (blockIdx.x >> 1) << 7;
  const int m0 = (blockIdx.x & 1) << 7;
  const int lane = t & 63, wv = t >> 6;
  const int m15 = lane & 15, quad = lane >> 4;
  const int wm = (wv & 1) << 6, wn = (wv >> 1) << 6;
  const size_t base = (size_t)bh * 393216;
  f32x4 acc[4][4];
  f32x4 z = {0.f,0.f,0.f,0.f};
  #pragma unroll
  for (int i = 0; i < 4; i++)
    #pragma unroll
    for (int j = 0; j < 4; j++) acc[i][j] = z;

  for (int s = 0; s < 24; s++){
    __syncthreads();
    for (int j = t; j < 1024; j += 256){
      int hf = j >> 9, jj = j & 511;
      int kp = jj >> 4, nc = jj & 15;
      const unsigned short* src = (hf ? Kd : Qd) + base
        + (size_t)(s * 64 + 2 * kp) * 256 + (hf ? m0 : n0) + nc * 8;
      uint4 q0 = *(const uint4*)src;
      uint4 q1 = *(const uint4*)(src + 256);
      const unsigned short* u0 = (const unsigned short*)&q0;
      const unsigned short* u1 = (const unsigned short*)&q1;
      unsigned* dst = (unsigned*)(hf ? sb : sa);
      int cx = (nc & 7) << 2;
      #pragma unroll
      for (int i = 0; i < 8; i++)
        dst[(nc * 8 + i) * 36 + (kp ^ cx)] = (unsigned)u0[i] | ((unsigned)u1[i] << 16);
    }
    __syncthreads();
    #pragma unroll
    for (int ks = 0; ks < 2; ks++){
      short8 afr[4], bfr[4];
      #pragma unroll
      for (int i = 0; i < 4; i++){
        int ra = wm + i * 16 + m15;
        int rb = wn + i * 16 + m15;
        afr[i] = *(const short8*)(sa + ra * 72 + (((4 * ks + quad) ^ ((ra >> 3) & 7)) << 3));
        bfr[i] = *(const short8*)(sb + rb * 72 + (((4 * ks + quad) ^ ((rb >> 3) & 7)) << 3));
      }
      #pragma unroll
      for (int mi = 0; mi < 4; mi++)
        #pragma unroll
        for (int ni = 0; ni < 4; ni++)
          acc[mi][ni] = __builtin_amdgcn_mfma_f32_16x16x32_bf16(afr[mi], bfr[ni], acc[mi][ni], 0, 0, 0);
    }
  }
  #pragma unroll
  for (int mi = 0; mi < 4; mi++)
    #pragma unroll
    for (int ni = 0; ni < 4; ni++)
      #pragma unroll
      for (int r = 0; r < 4; r++){
        int nr = n0 + wm + mi * 16 + quad * 4 + r;
        int mc = m0 + wn + ni * 16 + m15;
        S[(size_t)bh * 65536 + (size_t)nr * 256 + mc] = acc[mi][ni][r];
      }
}

// ---------------------------------------------------------------------------
// K4: softmax_1 with l2-norm scaling + temperature (sums norm partials).
// ---------------------------------------------------------------------------
__global__ __launch_bounds__(256) void k_softmax(const float* __restrict__ S,
                                                 const float* __restrict__ nqp,
                                                 const float* __restrict__ nkp,
                                                 const float* __restrict__ temp,
                                                 unsigned short* __restrict__ P)
{
  const int t = threadIdx.x, lane = t & 63, wv = t >> 6;
  const int bh = blockIdx.y;
  const int n = blockIdx.x * 4 + wv;
  const float tp = temp[bh & 7];
  const size_t ro = (size_t)bh * 65536 + (size_t)n * 256;
  float4 sv = *(const float4*)(S + ro + lane * 4);
  float4 ka = *(const float4*)(nkp + (size_t)bh * 256 + lane * 4);
  float4 kb = *(const float4*)(nkp + 16384 + (size_t)bh * 256 + lane * 4);
  float nqv = nqp[(size_t)bh * 256 + n] + nqp[16384 + (size_t)bh * 256 + n];
  float qi = tp / fmaxf(sqrtf(fmaxf(nqv, 0.f)), 1e-12f);
  float i0 = 1.f / fmaxf(sqrtf(fmaxf(ka.x + kb.x, 0.f)), 1e-12f);
  float i1 = 1.f / fmaxf(sqrtf(fmaxf(ka.y + kb.y, 0.f)), 1e-12f);
  float i2 = 1.f / fmaxf(sqrtf(fmaxf(ka.z + kb.z, 0.f)), 1e-12f);
  float i3 = 1.f / fmaxf(sqrtf(fmaxf(ka.w + kb.w, 0.f)), 1e-12f);
  float e0 = __expf(fminf(sv.x * qi * i0, 60.f));
  float e1 = __expf(fminf(sv.y * qi * i1, 60.f));
  float e2 = __expf(fminf(sv.z * qi * i2, 60.f));
  float e3 = __expf(fminf(sv.w * qi * i3, 60.f));
  float ss = e0 + e1 + e2 + e3;
  #pragma unroll
  for (int o = 32; o > 0; o >>= 1) ss += __shfl_xor(ss, o);
  float inv = 1.f / (ss + 1.f);
  uint2 pv;
  pv.x = (unsigned)f2bf(e0 * inv) | ((unsigned)f2bf(e1 * inv) << 16);
  pv.y = (unsigned)f2bf(e2 * inv) | ((unsigned)f2bf(e3 * inv) << 16);
  *(uint2*)(P + ro + lane * 4) = pv;
}

// ---------------------------------------------------------------------------
// K5: O[bh][d][n] = sum_m V[bh][d][m] * P[bh][n][m]. 128x128/block, grid(24,64).
// ---------------------------------------------------------------------------
__global__ __launch_bounds__(256) void k_ogemm(const unsigned short* __restrict__ Vd,
                                               const unsigned short* __restrict__ P,
                                               unsigned short* __restrict__ Od)
{
  __shared__ unsigned short sm[18432];
  unsigned short* const sa = sm;
  unsigned short* const sb = sm + 9216;
  const int t = threadIdx.x;
  const int bh = blockIdx.y;
  const int d0 = (blockIdx.x >> 1) << 7;
  const int n0 = (blockIdx.x & 1) << 7;
  const int lane = t & 63, wv = t >> 6;
  const int m15 = lane & 15, quad = lane >> 4;
  const int wm = (wv & 1) << 6, wn = (wv >> 1) << 6;
  f32x4 acc[4][4];
  f32x4 z = {0.f,0.f,0.f,0.f};
  #pragma unroll
  for (int i = 0; i < 4; i++)
    #pragma unroll
    for (int j = 0; j < 4; j++) acc[i][j] = z;

  for (int s = 0; s < 4; s++){
    __syncthreads();
    for (int j = t; j < 512; j += 256){
      int hf = j >> 8, jj = j & 255;
      int row = jj >> 1, hh = jj & 1;
      const unsigned short* src = hf
        ? (P  + (size_t)bh * 65536  + (size_t)(n0 + row) * 256 + s * 64 + hh * 32)
        : (Vd + (size_t)bh * 393216 + (size_t)(d0 + row) * 256 + s * 64 + hh * 32);
      uint4 v0 = *(const uint4*)src;
      uint4 v1 = *(const uint4*)(src + 8);
      uint4 v2 = *(const uint4*)(src + 16);
      uint4 v3 = *(const uint4*)(src + 24);
      unsigned* dst = (unsigned*)(hf ? sb : sa) + row * 36 + hh * 16;
      *(uint4*)dst        = v0;
      *(uint4*)(dst + 4)  = v1;
      *(uint4*)(dst + 8)  = v2;
      *(uint4*)(dst + 12) = v3;
    }
    __syncthreads();
    #pragma unroll
    for (int ks = 0; ks < 2; ks++){
      short8 afr[4], bfr[4];
      #pragma unroll
      for (int i = 0; i < 4; i++){
        afr[i] = *(const short8*)(sa + (wm + i * 16 + m15) * 72 + ks * 32 + quad * 8);
        bfr[i] = *(const short8*)(sb + (wn + i * 16 + m15) * 72 + ks * 32 + quad * 8);
      }
      #pragma unroll
      for (int mi = 0; mi < 4; mi++)
        #pragma unroll
        for (int ni = 0; ni < 4; ni++)
          acc[mi][ni] = __builtin_amdgcn_mfma_f32_16x16x32_bf16(afr[mi], bfr[ni], acc[mi][ni], 0, 0, 0);
    }
  }
  __syncthreads();
  #pragma unroll
  for (int mi = 0; mi < 4; mi++)
    #pragma unroll
    for (int ni = 0; ni < 4; ni++)
      #pragma unroll
      for (int r = 0; r < 4; r++)
        sm[(wm + mi * 16 + quad * 4 + r) * 136 + wn + ni * 16 + m15] = f2bf(acc[mi][ni][r]);
  __syncthreads();
  {
    int row = t >> 1, hh = t & 1;
    const unsigned short* lp = sm + row * 136 + hh * 64;
    unsigned short* gp = Od + (size_t)bh * 393216 + (size_t)(d0 + row) * 256 + n0 + hh * 64;
    #pragma unroll
    for (int u = 0; u < 8; u++)
      *(uint4*)(gp + u * 8) = *(const uint4*)(lp + u * 8);
  }
}

// ---------------------------------------------------------------------------
// K6: out[b][o][y][x] = sum_c48 wp[o][c] * Osp[b][c][y][x]. grid (16,16,8).
// ---------------------------------------------------------------------------
__global__ __launch_bounds__(256) void k_proj(const unsigned short* __restrict__ Od,
                                              const float* __restrict__ wp,
                                              float* __restrict__ out)
{
  __shared__ unsigned short sm6[21888];   // B[256][72]@0 + A[48][72]@18432; reuse lo fp32[16][264]
  unsigned short* const lb = sm6;
  unsigned short* const la = sm6 + 18432;
  float* const lo = (float*)sm6;
  const int t = threadIdx.x;
  const int w = blockIdx.x, h = blockIdx.y, b = blockIdx.z;
  for (int j = t; j < 10944; j += 256) ((unsigned*)sm6)[j] = 0u;
  __syncthreads();
  for (int j = t; j < 2304; j += 256){
    int m = j / 48, k = j - m * 48;
    la[m * 72 + k] = f2bf(wp[j]);
  }
  for (int j = t; j < 768; j += 256){
    int cp = j >> 5, nc = j & 31;
    int ch0 = 2 * cp;
    int head = ch0 / 6, cc = ch0 - head * 6;
    const unsigned short* r0 = Od + (((size_t)(b * 8 + head)) * 1536 + cc * 256 + h * 16 + w) * 256 + nc * 8;
    uint4 q0 = *(const uint4*)r0;
    uint4 q1 = *(const uint4*)(r0 + 65536);  // channel+1 = d+256 -> +65536 shorts
    const unsigned short* u0 = (const unsigned short*)&q0;
    const unsigned short* u1 = (const unsigned short*)&q1;
    unsigned* dst = (unsigned*)lb;
    int cx = (nc & 7) << 2;
    #pragma unroll
    for (int i = 0; i < 8; i++)
      dst[(nc * 8 + i) * 36 + (cp ^ cx)] = (unsigned)u0[i] | ((unsigned)u1[i] << 16);
  }
  __syncthreads();

  const int lane = t & 63, wv = t >> 6;
  const int m15 = lane & 15, quad = lane >> 4;
  const int n0w = wv << 6;
  f32x4 acc[3][4];
  f32x4 z = {0.f,0.f,0.f,0.f};
  #pragma unroll
  for (int i = 0; i < 3; i++)
    #pragma unroll
    for (int j = 0; j < 4; j++) acc[i][j] = z;
  #pragma unroll
  for (int ks = 0; ks < 2; ks++){
    short8 bfr[4];
    #pragma unroll
    for (int nt = 0; nt < 4; nt++){
      int rb = n0w + nt * 16 + m15;
      bfr[nt] = *(const short8*)(lb + rb * 72 + (((4 * ks + quad) ^ ((rb >> 3) & 7)) << 3));
    }
    #pragma unroll
    for (int mt = 0; mt < 3; mt++){
      short8 afr = *(const short8*)(la + (mt * 16 + m15) * 72 + ks * 32 + quad * 8);
      #pragma unroll
      for (int nt = 0; nt < 4; nt++)
        acc[mt][nt] = __builtin_amdgcn_mfma_f32_16x16x32_bf16(afr, bfr[nt], acc[mt][nt], 0, 0, 0);
    }
  }
  for (int mt = 0; mt < 3; mt++){
    __syncthreads();
    #pragma unroll
    for (int nt = 0; nt < 4; nt++)
      #pragma unroll
      for (int r = 0; r < 4; r++){
        int n = n0w + nt * 16 + m15;
        lo[(quad * 4 + r) * 264 + ((n & 0xF0) | ((n & 15) ^ (n >> 4)))] = acc[mt][nt][r];
      }
    __syncthreads();
    int fy = t >> 4, fx = t & 15;
    #pragma unroll
    for (int r = 0; r < 16; r++){
      float v = lo[r * 264 + fx * 16 + (fy ^ fx)];
      out[((size_t)(b * 48 + mt * 16 + r)) * 65536 + (h * 16 + fy) * 256 + w * 16 + fx] = v;
    }
  }
}

// ---------------------------------------------------------------------------
extern "C" void kernel_launch(void* const* d_in, const int* in_sizes, int n_in,
                              void* d_out, int out_size, void* d_ws, size_t ws_size,
                              hipStream_t stream)
{
  (void)in_sizes; (void)n_in; (void)out_size; (void)ws_size;
  const float* x  = (const float*)d_in[0];
  const float* wq = (const float*)d_in[1];
  const float* wd = (const float*)d_in[2];
  const float* wp = (const float*)d_in[3];
  const float* tp = (const float*)d_in[4];
  float* out = (float*)d_out;
  char* ws = (char*)d_ws;

  unsigned short* qs = (unsigned short*)ws;                  // [0, 50.33 MB) scratch per split
  unsigned short* Qd = (unsigned short*)(ws + 50331648);
  unsigned short* Kd = (unsigned short*)(ws + 100663296);
  unsigned short* Vd = (unsigned short*)(ws + 150994944);
  float*          S  = (float*)ws;                           // reuses qs region (dead)
  unsigned short* P  = (unsigned short*)(ws + 16777216);
  float*          nqp = (float*)(ws + 25165824);             // [2][64][256] = 128 KB
  float*          nkp = (float*)(ws + 25296896);             // [2][64][256] = 128 KB
  unsigned short* Od = Qd;                                   // reuses Qd (dead after sgemm/norms)
  unsigned short* toks[3] = {Qd, Kd, Vd};

  for (int split = 0; split < 3; split++){
    k_qkv1<<<4096,             256, 0, stream>>>(x, wq + split * 2304, qs);
    k_dw  <<<dim3(2, 16, 96),  256, 0, stream>>>(qs, wd + split * 432, toks[split]);
  }
  k_sgemm  <<<dim3(4, 64),     256, 0, stream>>>(Qd, Kd, S);
  k_norms  <<<dim3(64, 2, 2),  256, 0, stream>>>(Qd, Kd, nqp, nkp);
  k_softmax<<<dim3(64, 64),    256, 0, stream>>>(S, nqp, nkp, tp, P);
  k_ogemm  <<<dim3(24, 64),    256, 0, stream>>>(Vd, P, Od);
  k_proj   <<<dim3(16, 16, 8), 256, 0, stream>>>(Od, wp, out);
}

// Round 6
// 474.360 us; speedup vs baseline: 2.1303x; 1.5225x over previous
//
#include <hip/hip_runtime.h>
#include <stdint.h>

// ---------------------------------------------------------------------------
// Attention_global: B=8,C=48,H=W=256,HEADS=8,FCT=16 -> per (b,head): N=256
// tokens (n=fx*16+fy), d=1536 (d=c*256+h*16+w), c=6.
// R6: merged k_qkv (M=144, reads x once); k_dw re-tiled: bf16 LDS tile,
// 2ch/block, vector staging, one launch for all 144 channels.
// ws peak = 301,989,888 bytes (known-safe: R0 ran at 327 MB).
// ---------------------------------------------------------------------------

#define DI __device__ __forceinline__
typedef __attribute__((ext_vector_type(8))) short short8;
typedef __attribute__((ext_vector_type(4))) float f32x4;
typedef __attribute__((ext_vector_type(4))) unsigned short us4;

DI unsigned short f2bf(float f){
  unsigned u = __float_as_uint(f);
  unsigned r = (u + 0x7FFFu + ((u >> 16) & 1u)) >> 16;
  return (unsigned short)r;
}
DI float bf2f(unsigned short h){ return __uint_as_float(((unsigned)h) << 16); }

// ---------------------------------------------------------------------------
// K1a: qkv[b][o][p] = sum_c wq[o][c] * x[b][c][p], o in [0,144).
// MFMA M=144,K=48(pad 64),N=128 px/block. grid 4096.
// ---------------------------------------------------------------------------
__global__ __launch_bounds__(256) void k_qkv(const float* __restrict__ x,
                                             const float* __restrict__ wq,
                                             unsigned short* __restrict__ qkv)
{
  __shared__ unsigned short sm[19584]; // A[144][72]@0 + B[128][72]@10368; reuse D[144][136]
  unsigned short* const lA = sm;
  unsigned short* const lB = sm + 10368;
  const int t = threadIdx.x;
  const int g0 = blockIdx.x << 7;
  const int b  = g0 >> 16;
  const int p0 = g0 & 65535;

  for (int i = t; i < 9792; i += 256) ((unsigned*)sm)[i] = 0u; // k-pad must be 0
  __syncthreads();
  for (int j = t; j < 6912; j += 256){
    int m = j / 48, k = j - m * 48;
    lA[m * 72 + k] = f2bf(wq[j]);
  }
  // B = x^T tile [pixel][k=c]: bf16-pair pack + XOR block swizzle
  for (int j = t; j < 384; j += 256){
    int cp = j >> 4, nc = j & 15;
    const float* xr = x + ((size_t)(b * 48 + 2 * cp)) * 65536 + p0 + nc * 8;
    float4 a0 = *(const float4*)xr;
    float4 a1 = *(const float4*)(xr + 4);
    float4 b0 = *(const float4*)(xr + 65536);
    float4 b1 = *(const float4*)(xr + 65536 + 4);
    float r0[8] = {a0.x,a0.y,a0.z,a0.w,a1.x,a1.y,a1.z,a1.w};
    float r1[8] = {b0.x,b0.y,b0.z,b0.w,b1.x,b1.y,b1.z,b1.w};
    unsigned* dst = (unsigned*)lB;
    int cx = (nc & 7) << 2;
    #pragma unroll
    for (int i = 0; i < 8; i++)
      dst[(nc * 8 + i) * 36 + (cp ^ cx)] =
        (unsigned)f2bf(r0[i]) | ((unsigned)f2bf(r1[i]) << 16);
  }
  __syncthreads();

  const int lane = t & 63, wv = t >> 6;
  const int m15 = lane & 15, quad = lane >> 4;
  const int nw = wv << 5;
  f32x4 acc[9][2];
  f32x4 z = {0.f,0.f,0.f,0.f};
  #pragma unroll
  for (int i = 0; i < 9; i++){ acc[i][0] = z; acc[i][1] = z; }

  #pragma unroll
  for (int ks = 0; ks < 2; ks++){
    short8 bfr[2];
    #pragma unroll
    for (int nt = 0; nt < 2; nt++){
      int row = nw + nt * 16 + m15;
      bfr[nt] = *(const short8*)(lB + row * 72 + (((4 * ks + quad) ^ ((row >> 3) & 7)) << 3));
    }
    #pragma unroll
    for (int mt = 0; mt < 9; mt++){
      short8 afr = *(const short8*)(lA + (mt * 16 + m15) * 72 + ks * 32 + quad * 8);
      acc[mt][0] = __builtin_amdgcn_mfma_f32_16x16x32_bf16(afr, bfr[0], acc[mt][0], 0, 0, 0);
      acc[mt][1] = __builtin_amdgcn_mfma_f32_16x16x32_bf16(afr, bfr[1], acc[mt][1], 0, 0, 0);
    }
  }
  __syncthreads();
  #pragma unroll
  for (int mt = 0; mt < 9; mt++)
    #pragma unroll
    for (int nt = 0; nt < 2; nt++)
      #pragma unroll
      for (int r = 0; r < 4; r++)
        sm[(mt * 16 + quad * 4 + r) * 136 + nw + nt * 16 + m15] = f2bf(acc[mt][nt][r]);
  __syncthreads();
  for (int j = t; j < 2304; j += 256){
    int o = j >> 4, oc = j & 15;
    *(uint4*)(qkv + ((size_t)(b * 144 + o)) * 65536 + p0 + oc * 8) =
      *(const uint4*)(sm + o * 136 + oc * 8);
  }
}

// ---------------------------------------------------------------------------
// K1b: depthwise 3x3 (SAME) over qkv (144 ch); writes Q/K/V tokens bf16.
// grid (2, 16, 8*72): z = b*72+g, ch0=2g. 2 channels/block, bf16 LDS tile.
// Tile row layout: halo col -1 at idx 7, interior x at 8+x, halo 128 at 136.
// ---------------------------------------------------------------------------
__global__ __launch_bounds__(256, 6) void k_dw(const unsigned short* __restrict__ qkv,
                                               const float* __restrict__ wd,
                                               unsigned short* __restrict__ tok0)
{
  __shared__ unsigned short tile[5184];   // 2ch x 18 x 144
  __shared__ unsigned short lout[4224];   // 2ch x 8wt x 264 (swizzled tokens)
  const int t = threadIdx.x;
  const int wg = blockIdx.x, h = blockIdx.y;
  const int b = blockIdx.z / 72, g = blockIdx.z % 72;
  const int ch0 = g * 2;
  const int y0 = h << 4, xg = wg << 7;

  // interior staging: 36 row-ch x 16 segs, uint4 (8 shorts) each
  for (int j = t; j < 576; j += 256){
    int rowch = j >> 4, seg = j & 15;
    int cl = rowch >= 18, row = rowch - cl * 18;
    int y = y0 - 1 + row;
    uint4 v = {0u,0u,0u,0u};
    if ((unsigned)y < 256u)
      v = *(const uint4*)(qkv + ((size_t)(b*144 + ch0 + cl))*65536 + y*256 + xg + seg*8);
    *(uint4*)(tile + cl*2592 + row*144 + 8 + seg*8) = v;
  }
  // halo cols (-1 -> idx7, 128 -> idx136)
  if (t < 72){
    int rowch = t >> 1, side = t & 1;
    int cl = rowch >= 18, row = rowch - cl * 18;
    int y = y0 - 1 + row;
    int xx = side ? (xg + 128) : (xg - 1);
    unsigned short v = 0;
    if ((unsigned)y < 256u && (unsigned)xx < 256u)
      v = qkv[((size_t)(b*144 + ch0 + cl))*65536 + y*256 + xx];
    tile[cl*2592 + row*144 + (side ? 136 : 7)] = v;
  }
  __syncthreads();

  const int xt = t & 31, ys = t >> 5;   // 4 px (x0=4xt), 2 rows (2ys,2ys+1)
  const int x0 = xt << 2;
  #pragma unroll
  for (int cl = 0; cl < 2; cl++){
    int ch = ch0 + cl;
    float w9[9];
    #pragma unroll
    for (int i = 0; i < 9; i++) w9[i] = wd[ch * 9 + i];    // wave-uniform
    float f[4][6];                                          // rows 2ys..2ys+3, cols x0-1..x0+4
    #pragma unroll
    for (int rr = 0; rr < 4; rr++){
      const unsigned short* rp = tile + cl*2592 + (2*ys + rr)*144;
      us4 m = *(const us4*)(rp + 8 + x0);
      unsigned short a = rp[7 + x0];
      unsigned short bb = rp[12 + x0];
      f[rr][0] = bf2f(a);
      f[rr][1] = bf2f(m.x); f[rr][2] = bf2f(m.y);
      f[rr][3] = bf2f(m.z); f[rr][4] = bf2f(m.w);
      f[rr][5] = bf2f(bb);
    }
    #pragma unroll
    for (int r = 0; r < 2; r++)
      #pragma unroll
      for (int k = 0; k < 4; k++){
        float s = 0.f;
        #pragma unroll
        for (int dy = 0; dy < 3; dy++)
          #pragma unroll
          for (int dx = 0; dx < 3; dx++)
            s = fmaf(f[r + dy][k + dx], w9[dy * 3 + dx], s);
        int xl = x0 + k, yo = 2 * ys + r;
        int n = ((xl & 15) << 4) + yo;
        lout[cl*2112 + (xl >> 4)*264 + ((n & 0xF0) | ((n & 15) ^ (n >> 4)))] = f2bf(s);
      }
  }
  __syncthreads();
  // coalesced token-layout writeback
  for (int j = t; j < 512; j += 256){
    int cl = j >> 8, wt = (j >> 5) & 7, oc = j & 31;
    int split = ch0 / 48;
    int chs = ch0 - split * 48 + cl;
    int head = chs / 6, cc = chs - head * 6;
    int d = cc * 256 + h * 16 + wg * 8 + wt;
    const unsigned short* lp = lout + cl * 2112 + wt * 264;
    unsigned short v8[8];
    #pragma unroll
    for (int i = 0; i < 8; i++){
      int n = oc * 8 + i;
      v8[i] = lp[(n & 0xF0) | ((n & 15) ^ (n >> 4))];
    }
    uint4 pk;
    pk.x = (unsigned)v8[0] | ((unsigned)v8[1] << 16);
    pk.y = (unsigned)v8[2] | ((unsigned)v8[3] << 16);
    pk.z = (unsigned)v8[4] | ((unsigned)v8[5] << 16);
    pk.w = (unsigned)v8[6] | ((unsigned)v8[7] << 16);
    *(uint4*)(tok0 + (size_t)split * 25165824
              + (((size_t)(b * 8 + head)) * 1536 + d) * 256 + oc * 8) = pk;
  }
}

// ---------------------------------------------------------------------------
// K2: norm partials. grid (64 bh, 2 tensor, 2 d-half), block 256.
// ---------------------------------------------------------------------------
__global__ __launch_bounds__(256) void k_norms(const unsigned short* __restrict__ Qd,
                                               const unsigned short* __restrict__ Kd,
                                               float* __restrict__ nqp,
                                               float* __restrict__ nkp)
{
  const int bh = blockIdx.x, half = blockIdx.z;
  const unsigned short* T = blockIdx.y ? Kd : Qd;
  float* N = blockIdx.y ? nkp : nqp;
  const int t = threadIdx.x, g = t & 7, tl = t >> 3;
  const unsigned short* p = T + (size_t)bh * 393216 + (size_t)(half * 768 + g) * 256 + tl * 8;
  float a[8] = {0.f,0.f,0.f,0.f,0.f,0.f,0.f,0.f};
  #pragma unroll 4
  for (int dd = 0; dd < 96; dd++){
    uint4 v = *(const uint4*)(p + (size_t)dd * 2048);
    const unsigned short* u = (const unsigned short*)&v;
    #pragma unroll
    for (int i = 0; i < 8; i++){ float f = bf2f(u[i]); a[i] = fmaf(f, f, a[i]); }
  }
  #pragma unroll
  for (int off = 1; off < 8; off <<= 1)
    #pragma unroll
    for (int i = 0; i < 8; i++) a[i] += __shfl_xor(a[i], off);
  if (g == 0){
    float* o = N + half * 16384 + bh * 256 + tl * 8;
    #pragma unroll
    for (int i = 0; i < 8; i++) o[i] = a[i];
  }
}

// ---------------------------------------------------------------------------
// K3: S[bh][n][m] = sum_d Q[bh][d][n]*K[bh][d][m]. 128x128/block, grid (4,64).
// ---------------------------------------------------------------------------
__global__ __launch_bounds__(256) void k_sgemm(const unsigned short* __restrict__ Qd,
                                               const unsigned short* __restrict__ Kd,
                                               float* __restrict__ S)
{
  __shared__ unsigned short sm[18432];
  unsigned short* const sa = sm;
  unsigned short* const sb = sm + 9216;
  const int t = threadIdx.x;
  const int bh = blockIdx.y;
  const int n0 = (blockIdx.x >> 1) << 7;
  const int m0 = (blockIdx.x & 1) << 7;
  const int lane = t & 63, wv = t >> 6;
  const int m15 = lane & 15, quad = lane >> 4;
  const int wm = (wv & 1) << 6, wn = (wv >> 1) << 6;
  const size_t base = (size_t)bh * 393216;
  f32x4 acc[4][4];
  f32x4 z = {0.f,0.f,0.f,0.f};
  #pragma unroll
  for (int i = 0; i < 4; i++)
    #pragma unroll
    for (int j = 0; j < 4; j++) acc[i][j] = z;

  for (int s = 0; s < 24; s++){
    __syncthreads();
    for (int j = t; j < 1024; j += 256){
      int hf = j >> 9, jj = j & 511;
      int kp = jj >> 4, nc = jj & 15;
      const unsigned short* src = (hf ? Kd : Qd) + base
        + (size_t)(s * 64 + 2 * kp) * 256 + (hf ? m0 : n0) + nc * 8;
      uint4 q0 = *(const uint4*)src;
      uint4 q1 = *(const uint4*)(src + 256);
      const unsigned short* u0 = (const unsigned short*)&q0;
      const unsigned short* u1 = (const unsigned short*)&q1;
      unsigned* dst = (unsigned*)(hf ? sb : sa);
      int cx = (nc & 7) << 2;
      #pragma unroll
      for (int i = 0; i < 8; i++)
        dst[(nc * 8 + i) * 36 + (kp ^ cx)] = (unsigned)u0[i] | ((unsigned)u1[i] << 16);
    }
    __syncthreads();
    #pragma unroll
    for (int ks = 0; ks < 2; ks++){
      short8 afr[4], bfr[4];
      #pragma unroll
      for (int i = 0; i < 4; i++){
        int ra = wm + i * 16 + m15;
        int rb = wn + i * 16 + m15;
        afr[i] = *(const short8*)(sa + ra * 72 + (((4 * ks + quad) ^ ((ra >> 3) & 7)) << 3));
        bfr[i] = *(const short8*)(sb + rb * 72 + (((4 * ks + quad) ^ ((rb >> 3) & 7)) << 3));
      }
      #pragma unroll
      for (int mi = 0; mi < 4; mi++)
        #pragma unroll
        for (int ni = 0; ni < 4; ni++)
          acc[mi][ni] = __builtin_amdgcn_mfma_f32_16x16x32_bf16(afr[mi], bfr[ni], acc[mi][ni], 0, 0, 0);
    }
  }
  #pragma unroll
  for (int mi = 0; mi < 4; mi++)
    #pragma unroll
    for (int ni = 0; ni < 4; ni++)
      #pragma unroll
      for (int r = 0; r < 4; r++){
        int nr = n0 + wm + mi * 16 + quad * 4 + r;
        int mc = m0 + wn + ni * 16 + m15;
        S[(size_t)bh * 65536 + (size_t)nr * 256 + mc] = acc[mi][ni][r];
      }
}

// ---------------------------------------------------------------------------
// K4: softmax_1 with l2-norm scaling + temperature (sums norm partials).
// ---------------------------------------------------------------------------
__global__ __launch_bounds__(256) void k_softmax(const float* __restrict__ S,
                                                 const float* __restrict__ nqp,
                                                 const float* __restrict__ nkp,
                                                 const float* __restrict__ temp,
                                                 unsigned short* __restrict__ P)
{
  const int t = threadIdx.x, lane = t & 63, wv = t >> 6;
  const int bh = blockIdx.y;
  const int n = blockIdx.x * 4 + wv;
  const float tp = temp[bh & 7];
  const size_t ro = (size_t)bh * 65536 + (size_t)n * 256;
  float4 sv = *(const float4*)(S + ro + lane * 4);
  float4 ka = *(const float4*)(nkp + (size_t)bh * 256 + lane * 4);
  float4 kb = *(const float4*)(nkp + 16384 + (size_t)bh * 256 + lane * 4);
  float nqv = nqp[(size_t)bh * 256 + n] + nqp[16384 + (size_t)bh * 256 + n];
  float qi = tp / fmaxf(sqrtf(fmaxf(nqv, 0.f)), 1e-12f);
  float i0 = 1.f / fmaxf(sqrtf(fmaxf(ka.x + kb.x, 0.f)), 1e-12f);
  float i1 = 1.f / fmaxf(sqrtf(fmaxf(ka.y + kb.y, 0.f)), 1e-12f);
  float i2 = 1.f / fmaxf(sqrtf(fmaxf(ka.z + kb.z, 0.f)), 1e-12f);
  float i3 = 1.f / fmaxf(sqrtf(fmaxf(ka.w + kb.w, 0.f)), 1e-12f);
  float e0 = __expf(fminf(sv.x * qi * i0, 60.f));
  float e1 = __expf(fminf(sv.y * qi * i1, 60.f));
  float e2 = __expf(fminf(sv.z * qi * i2, 60.f));
  float e3 = __expf(fminf(sv.w * qi * i3, 60.f));
  float ss = e0 + e1 + e2 + e3;
  #pragma unroll
  for (int o = 32; o > 0; o >>= 1) ss += __shfl_xor(ss, o);
  float inv = 1.f / (ss + 1.f);
  uint2 pv;
  pv.x = (unsigned)f2bf(e0 * inv) | ((unsigned)f2bf(e1 * inv) << 16);
  pv.y = (unsigned)f2bf(e2 * inv) | ((unsigned)f2bf(e3 * inv) << 16);
  *(uint2*)(P + ro + lane * 4) = pv;
}

// ---------------------------------------------------------------------------
// K5: O[bh][d][n] = sum_m V[bh][d][m] * P[bh][n][m]. 128x128/block, grid(24,64).
// ---------------------------------------------------------------------------
__global__ __launch_bounds__(256) void k_ogemm(const unsigned short* __restrict__ Vd,
                                               const unsigned short* __restrict__ P,
                                               unsigned short* __restrict__ Od)
{
  __shared__ unsigned short sm[18432];
  unsigned short* const sa = sm;
  unsigned short* const sb = sm + 9216;
  const int t = threadIdx.x;
  const int bh = blockIdx.y;
  const int d0 = (blockIdx.x >> 1) << 7;
  const int n0 = (blockIdx.x & 1) << 7;
  const int lane = t & 63, wv = t >> 6;
  const int m15 = lane & 15, quad = lane >> 4;
  const int wm = (wv & 1) << 6, wn = (wv >> 1) << 6;
  f32x4 acc[4][4];
  f32x4 z = {0.f,0.f,0.f,0.f};
  #pragma unroll
  for (int i = 0; i < 4; i++)
    #pragma unroll
    for (int j = 0; j < 4; j++) acc[i][j] = z;

  for (int s = 0; s < 4; s++){
    __syncthreads();
    for (int j = t; j < 512; j += 256){
      int hf = j >> 8, jj = j & 255;
      int row = jj >> 1, hh = jj & 1;
      const unsigned short* src = hf
        ? (P  + (size_t)bh * 65536  + (size_t)(n0 + row) * 256 + s * 64 + hh * 32)
        : (Vd + (size_t)bh * 393216 + (size_t)(d0 + row) * 256 + s * 64 + hh * 32);
      uint4 v0 = *(const uint4*)src;
      uint4 v1 = *(const uint4*)(src + 8);
      uint4 v2 = *(const uint4*)(src + 16);
      uint4 v3 = *(const uint4*)(src + 24);
      unsigned* dst = (unsigned*)(hf ? sb : sa) + row * 36 + hh * 16;
      *(uint4*)dst        = v0;
      *(uint4*)(dst + 4)  = v1;
      *(uint4*)(dst + 8)  = v2;
      *(uint4*)(dst + 12) = v3;
    }
    __syncthreads();
    #pragma unroll
    for (int ks = 0; ks < 2; ks++){
      short8 afr[4], bfr[4];
      #pragma unroll
      for (int i = 0; i < 4; i++){
        afr[i] = *(const short8*)(sa + (wm + i * 16 + m15) * 72 + ks * 32 + quad * 8);
        bfr[i] = *(const short8*)(sb + (wn + i * 16 + m15) * 72 + ks * 32 + quad * 8);
      }
      #pragma unroll
      for (int mi = 0; mi < 4; mi++)
        #pragma unroll
        for (int ni = 0; ni < 4; ni++)
          acc[mi][ni] = __builtin_amdgcn_mfma_f32_16x16x32_bf16(afr[mi], bfr[ni], acc[mi][ni], 0, 0, 0);
    }
  }
  __syncthreads();
  #pragma unroll
  for (int mi = 0; mi < 4; mi++)
    #pragma unroll
    for (int ni = 0; ni < 4; ni++)
      #pragma unroll
      for (int r = 0; r < 4; r++)
        sm[(wm + mi * 16 + quad * 4 + r) * 136 + wn + ni * 16 + m15] = f2bf(acc[mi][ni][r]);
  __syncthreads();
  {
    int row = t >> 1, hh = t & 1;
    const unsigned short* lp = sm + row * 136 + hh * 64;
    unsigned short* gp = Od + (size_t)bh * 393216 + (size_t)(d0 + row) * 256 + n0 + hh * 64;
    #pragma unroll
    for (int u = 0; u < 8; u++)
      *(uint4*)(gp + u * 8) = *(const uint4*)(lp + u * 8);
  }
}

// ---------------------------------------------------------------------------
// K6: out[b][o][y][x] = sum_c48 wp[o][c] * Osp[b][c][y][x]. grid (16,16,8).
// ---------------------------------------------------------------------------
__global__ __launch_bounds__(256) void k_proj(const unsigned short* __restrict__ Od,
                                              const float* __restrict__ wp,
                                              float* __restrict__ out)
{
  __shared__ unsigned short sm6[21888];   // B[256][72]@0 + A[48][72]@18432; reuse lo fp32[16][264]
  unsigned short* const lb = sm6;
  unsigned short* const la = sm6 + 18432;
  float* const lo = (float*)sm6;
  const int t = threadIdx.x;
  const int w = blockIdx.x, h = blockIdx.y, b = blockIdx.z;
  for (int j = t; j < 10944; j += 256) ((unsigned*)sm6)[j] = 0u;
  __syncthreads();
  for (int j = t; j < 2304; j += 256){
    int m = j / 48, k = j - m * 48;
    la[m * 72 + k] = f2bf(wp[j]);
  }
  for (int j = t; j < 768; j += 256){
    int cp = j >> 5, nc = j & 31;
    int ch0 = 2 * cp;
    int head = ch0 / 6, cc = ch0 - head * 6;
    const unsigned short* r0 = Od + (((size_t)(b * 8 + head)) * 1536 + cc * 256 + h * 16 + w) * 256 + nc * 8;
    uint4 q0 = *(const uint4*)r0;
    uint4 q1 = *(const uint4*)(r0 + 65536);  // channel+1 = d+256 -> +65536 shorts
    const unsigned short* u0 = (const unsigned short*)&q0;
    const unsigned short* u1 = (const unsigned short*)&q1;
    unsigned* dst = (unsigned*)lb;
    int cx = (nc & 7) << 2;
    #pragma unroll
    for (int i = 0; i < 8; i++)
      dst[(nc * 8 + i) * 36 + (cp ^ cx)] = (unsigned)u0[i] | ((unsigned)u1[i] << 16);
  }
  __syncthreads();

  const int lane = t & 63, wv = t >> 6;
  const int m15 = lane & 15, quad = lane >> 4;
  const int n0w = wv << 6;
  f32x4 acc[3][4];
  f32x4 z = {0.f,0.f,0.f,0.f};
  #pragma unroll
  for (int i = 0; i < 3; i++)
    #pragma unroll
    for (int j = 0; j < 4; j++) acc[i][j] = z;
  #pragma unroll
  for (int ks = 0; ks < 2; ks++){
    short8 bfr[4];
    #pragma unroll
    for (int nt = 0; nt < 4; nt++){
      int rb = n0w + nt * 16 + m15;
      bfr[nt] = *(const short8*)(lb + rb * 72 + (((4 * ks + quad) ^ ((rb >> 3) & 7)) << 3));
    }
    #pragma unroll
    for (int mt = 0; mt < 3; mt++){
      short8 afr = *(const short8*)(la + (mt * 16 + m15) * 72 + ks * 32 + quad * 8);
      #pragma unroll
      for (int nt = 0; nt < 4; nt++)
        acc[mt][nt] = __builtin_amdgcn_mfma_f32_16x16x32_bf16(afr, bfr[nt], acc[mt][nt], 0, 0, 0);
    }
  }
  for (int mt = 0; mt < 3; mt++){
    __syncthreads();
    #pragma unroll
    for (int nt = 0; nt < 4; nt++)
      #pragma unroll
      for (int r = 0; r < 4; r++){
        int n = n0w + nt * 16 + m15;
        lo[(quad * 4 + r) * 264 + ((n & 0xF0) | ((n & 15) ^ (n >> 4)))] = acc[mt][nt][r];
      }
    __syncthreads();
    int fy = t >> 4, fx = t & 15;
    #pragma unroll
    for (int r = 0; r < 16; r++){
      float v = lo[r * 264 + fx * 16 + (fy ^ fx)];
      out[((size_t)(b * 48 + mt * 16 + r)) * 65536 + (h * 16 + fy) * 256 + w * 16 + fx] = v;
    }
  }
}

// ---------------------------------------------------------------------------
extern "C" void kernel_launch(void* const* d_in, const int* in_sizes, int n_in,
                              void* d_out, int out_size, void* d_ws, size_t ws_size,
                              hipStream_t stream)
{
  (void)in_sizes; (void)n_in; (void)out_size; (void)ws_size;
  const float* x  = (const float*)d_in[0];
  const float* wq = (const float*)d_in[1];
  const float* wd = (const float*)d_in[2];
  const float* wp = (const float*)d_in[3];
  const float* tp = (const float*)d_in[4];
  float* out = (float*)d_out;
  char* ws = (char*)d_ws;

  unsigned short* qkv = (unsigned short*)ws;                 // [0, 151 MB)
  unsigned short* Qd  = (unsigned short*)(ws + 150994944);   // tokens (contiguous Q,K,V)
  unsigned short* Kd  = (unsigned short*)(ws + 201326592);
  unsigned short* Vd  = (unsigned short*)(ws + 251658240);
  float*          S   = (float*)ws;                          // reuses qkv (dead after k_dw)
  unsigned short* P   = (unsigned short*)(ws + 16777216);
  float*          nqp = (float*)(ws + 25165824);             // [2][64][256]
  float*          nkp = (float*)(ws + 25296896);
  unsigned short* Od  = Qd;                                  // reuses Qd (dead after sgemm/norms)

  k_qkv    <<<4096,              256, 0, stream>>>(x, wq, qkv);
  k_dw     <<<dim3(2, 16, 576),  256, 0, stream>>>(qkv, wd, Qd);
  k_sgemm  <<<dim3(4, 64),       256, 0, stream>>>(Qd, Kd, S);
  k_norms  <<<dim3(64, 2, 2),    256, 0, stream>>>(Qd, Kd, nqp, nkp);
  k_softmax<<<dim3(64, 64),      256, 0, stream>>>(S, nqp, nkp, tp, P);
  k_ogemm  <<<dim3(24, 64),      256, 0, stream>>>(Vd, P, Od);
  k_proj   <<<dim3(16, 16, 8),   256, 0, stream>>>(Od, wp, out);
}